// Round 12
// baseline (905.586 us; speedup 1.0000x reference)
//
#include <hip/hip_runtime.h>
#include <hip/hip_bf16.h>

typedef __hip_bfloat16 bf16;

typedef __bf16 bf16x8 __attribute__((ext_vector_type(8)));
typedef float  f32x16 __attribute__((ext_vector_type(16)));

static __device__ __forceinline__ float bf(const bf16 v){ return __bfloat162float(v); }
static __device__ __forceinline__ float bfu(unsigned short u){
  unsigned fw = ((unsigned)u) << 16; float v; __builtin_memcpy(&v, &fw, 4); return v;
}

// flag f: 0 = bf16, 1 = fp32
static __device__ __forceinline__ float ldm(const void* p, long i, int f){
  return f ? ((const float*)p)[i] : __bfloat162float(((const bf16*)p)[i]);
}
static __device__ __forceinline__ void stm(void* p, long i, int f, float v){
  if(f) ((float*)p)[i] = v; else ((bf16*)p)[i] = __float2bfloat16(v);
}
static __device__ __forceinline__ unsigned short bfbits(float v){
  __hip_bfloat16 h = __float2bfloat16(v);
  return *(unsigned short*)&h;
}

// ---------------- input dtype detector (bit-level correct) ----------------
__global__ void k_detect(const void* __restrict__ w, int* __restrict__ mode){
  if(blockIdx.x == 0 && threadIdx.x == 0){
    const unsigned int* u = (const unsigned int*)w;
    int saneLo = 0;
    for(int i = 0; i < 64; i++){
      unsigned short lo = (unsigned short)(u[i] & 0xFFFFu);
      unsigned int fw = ((unsigned int)lo) << 16;
      float v; __builtin_memcpy(&v, &fw, 4);
      float a = fabsf(v);
      if(a > 1e-7f && a < 100.f) saneLo++;
    }
    *mode = (saneLo >= 48) ? 0 : 1;   // 0 = bf16, 1 = fp32
  }
}

// ---------------- SAGE weights [o][c] (256x256) -> MFMA A-frag order, bf16 ----------------
// wF[(kc*8 + nc)*512 + L*8 + e] = w[o][c], o = nc*32+(L&31), c = kc*16+(L>>5)*8+e.
__global__ void k_wtrans6(const void* __restrict__ w, bf16* __restrict__ wF,
                          const int* __restrict__ dmode){
  int idx = blockIdx.x * 256 + threadIdx.x;
  if(idx >= 65536) return;
  int dm = *dmode;
  int e = idx & 7;
  int L = (idx >> 3) & 63;
  int r = idx >> 9;
  int nc = r & 7;
  int kc = r >> 3;
  int o = nc*32 + (L & 31);
  int c = kc*16 + (L >> 5)*8 + e;
  wF[idx] = __float2bfloat16(ldm(w, (long)o*256 + c, dm));
}

// ---------------- convT weights [Cin,Cout,3,3] -> MFMA A-fragment order ----------------
// wF[((kc*9 + t)*NC + nc)*512 + L*8 + e] = w[ci][co][t] with
// ci = kc*16 + (L>>5)*8 + e, co = nc*32 + (L&31).
__global__ void k_wtrans4(const void* __restrict__ w, bf16* __restrict__ wF,
                          const int* __restrict__ dmode, int Cin, int Cout){
  int idx = blockIdx.x * 256 + threadIdx.x;
  if(idx >= Cin * Cout * 9) return;
  int dm = *dmode;
  int e = idx & 7;
  int L = (idx >> 3) & 63;
  int r = idx >> 9;
  int NC = Cout >> 5;
  int nc = r % NC; r /= NC;
  int t  = r % 9;
  int kc = r / 9;
  int ci = kc*16 + (L>>5)*8 + e;
  int co = nc*32 + (L&31);
  wF[idx] = __float2bfloat16(ldm(w, ((long)ci*Cout + co)*9 + t, dm));
}

// ---------------- conv weights [Cout,Cin,3,3] -> MFMA A-fragment order ----------------
// Same fragment layout as k_wtrans4, source indexed [co][ci][t].
__global__ void k_wtrans5(const void* __restrict__ w, bf16* __restrict__ wF,
                          const int* __restrict__ dmode, int Cin, int Cout){
  int idx = blockIdx.x * 256 + threadIdx.x;
  if(idx >= Cin * Cout * 9) return;
  int dm = *dmode;
  int e = idx & 7;
  int L = (idx >> 3) & 63;
  int r = idx >> 9;
  int NC = Cout >> 5;
  int nc = r % NC; r /= NC;
  int t  = r % 9;
  int kc = r / 9;
  int ci = kc*16 + (L>>5)*8 + e;
  int co = nc*32 + (L&31);
  wF[idx] = __float2bfloat16(ldm(w, ((long)co*Cin + ci)*9 + t, dm));
}

// ---------------- d4: Cin=1 conv 3x3 s=2, j-fast coalesced writes ----------------
// (r6 evidence: co-fast stores -> 545MB write-allocate, 10.7x ideal.)
__global__ __launch_bounds__(256, 4)
void k_conv_d4(const void* __restrict__ in, long in_off,
               const void* __restrict__ w, const void* __restrict__ bias,
               bf16* __restrict__ out, const int* __restrict__ dmode)
{
  __shared__ float sW[288];
  __shared__ float sB[32];
  int tid = threadIdx.x;
  int dm = *dmode;
  for(int e = tid; e < 288; e += 256) sW[e] = ldm(w, e, dm);  // w[co][0][kh][kw] -> co*9+t
  if(tid < 32)  sB[tid] = ldm(bias, tid, dm);
  __syncthreads();
  int r = tid / 50, jt = tid % 50;
  if(r >= 5) return;
  int ho = blockIdx.x * 5 + r;
  int b  = blockIdx.z;
  int j0 = jt * 4;

  float x[3][9];
  long ibase = in_off + (long)b * 160000;
  #pragma unroll
  for(int rr = 0; rr < 3; rr++){
    int ir = 2*ho - 1 + rr;
    if(ir < 0 || ir >= 400){
      #pragma unroll
      for(int c = 0; c < 9; c++) x[rr][c] = 0.f;
      continue;
    }
    long rb = ibase + (long)ir * 400;
    int c0 = 2*j0 - 1;
    #pragma unroll
    for(int c = 0; c < 9; c++){
      int ic = c0 + c;
      x[rr][c] = (ic >= 0 && ic < 400) ? ldm(in, rb + ic, dm) : 0.f;
    }
  }

  long obase = ((long)b * 32) * 40000 + (long)ho * 200 + j0;
  for(int co = 0; co < 32; co++){
    const float* wv = &sW[co*9];
    float bv = sB[co];
    float a[4];
    #pragma unroll
    for(int p = 0; p < 4; p++){
      float s = bv;
      #pragma unroll
      for(int kh = 0; kh < 3; kh++)
        #pragma unroll
        for(int kw = 0; kw < 3; kw++)
          s += x[kh][2*p + kw] * wv[kh*3 + kw];
      a[p] = s;
    }
    ushort4 pk;
    pk.x = bfbits(a[0]); pk.y = bfbits(a[1]); pk.z = bfbits(a[2]); pk.w = bfbits(a[3]);
    *(ushort4*)&out[obase + (long)co * 40000] = pk;
  }
}

// ---------------- Conv2d 3x3 stride-S — MFMA 32x32x16 ----------------
template<int CW, int NWC, int NWM, int S, int OCC>
__global__ __launch_bounds__(256, OCC)
void k_convSM(const void* __restrict__ in, long in_off, int fin_sel,
              const bf16* __restrict__ wF, const void* __restrict__ bias,
              void* __restrict__ out, int fout,
              const int* __restrict__ dmode,
              int Cin, int Hin, int Win, int Cout, int Hout, int Wout, int nym)
{
  constexpr int CP = 40;
  constexpr int HALF = CW/2;
  __shared__ unsigned short sX[3*CW*CP];
  int tid  = threadIdx.x;
  int lane = tid & 63;
  int wv   = tid >> 6;
  int nc   = wv % NWC;
  int mt   = wv / NWC;
  int ho   = blockIdx.x;
  int colg = blockIdx.y % nym;
  int cog  = blockIdx.y / nym;
  int b    = blockIdx.z;
  int dm   = *dmode;
  int fin  = (fin_sel == 2) ? dm : fin_sel;
  int NCtot = Cout >> 5;
  int chunk = cog*NWC + nc;
  int jl   = mt*32 + (lane & 31);
  int hi   = lane >> 5;
  int C0   = S*(colg*NWM*32);      // padded col c <-> input col C0-1+c
  int ir0  = S*ho - 1;

  f32x16 acc;
  #pragma unroll
  for(int q = 0; q < 16; q++) acc[q] = 0.f;

  int p0, p1, p2;
  if(S == 2){ p0 = jl; p1 = HALF + jl; p2 = jl + 1; }
  else      { p0 = jl; p1 = jl + 1;    p2 = jl + 2; }

  for(int ci0 = 0; ci0 < Cin; ci0 += 32){
    for(int e = tid; e < 12*CW; e += 256){
      int c  = e % CW;
      int s  = e / CW;
      int kg = s & 3, r = s >> 2;
      int ir = ir0 + r;
      int ic = C0 - 1 + c;
      unsigned pk0, pk1, pk2, pk3;
      if(ir >= 0 && ir < Hin && ic >= 0 && ic < Win){
        long step = (long)Hin*Win;
        long base = in_off + ((long)b*Cin + ci0 + kg*8)*step + (long)ir*Win + ic;
        unsigned short t8[8];
        #pragma unroll
        for(int u = 0; u < 8; u++) t8[u] = bfbits(ldm(in, base + u*step, fin));
        pk0 = t8[0] | ((unsigned)t8[1]<<16);
        pk1 = t8[2] | ((unsigned)t8[3]<<16);
        pk2 = t8[4] | ((unsigned)t8[5]<<16);
        pk3 = t8[6] | ((unsigned)t8[7]<<16);
      } else { pk0=0; pk1=0; pk2=0; pk3=0; }
      int pos = (S == 2) ? ((c&1) ? HALF + (c>>1) : (c>>1)) : c;
      uint4 q; q.x=pk0; q.y=pk1; q.z=pk2; q.w=pk3;
      *(uint4*)&sX[(r*CW + pos)*CP + kg*8] = q;
    }
    __syncthreads();

    #pragma unroll
    for(int kg2 = 0; kg2 < 2; kg2++){
      int kbase = 8*hi + kg2*16;
      bf16x8 x[9];
      #pragma unroll
      for(int r = 0; r < 3; r++){
        x[r*3+0] = *(const bf16x8*)&sX[(r*CW + p0)*CP + kbase];
        x[r*3+1] = *(const bf16x8*)&sX[(r*CW + p1)*CP + kbase];
        x[r*3+2] = *(const bf16x8*)&sX[(r*CW + p2)*CP + kbase];
      }
      int kc = (ci0 >> 4) + kg2;
      const bf16x8* wb = ((const bf16x8*)wF) + ((long)(kc*9)*NCtot + chunk)*64 + lane;
      const long ws = (long)NCtot*64;
      #pragma unroll
      for(int t = 0; t < 9; t++){
        bf16x8 w = wb[(long)t*ws];
        acc = __builtin_amdgcn_mfma_f32_32x32x16_bf16(w, x[t], acc, 0,0,0);
      }
    }
    __syncthreads();
  }

  int j = colg*NWM*32 + jl;
  if(j < Wout){
    #pragma unroll
    for(int r16 = 0; r16 < 16; r16++){
      int co = chunk*32 + (r16&3) + 8*(r16>>2) + 4*hi;
      float bv = ldm(bias, co, dm);
      stm(out, ((long)b*Cout + co)*Hout*Wout + (long)ho*Wout + j, fout, acc[r16] + bv);
    }
  }
}

// ---------------- InstanceNorm (affine=False) + PReLU, in place ----------------
// r9: scalar 2-pass bf16 loads ran at 11% of BW. Vectorized ushort4 both passes.
__global__ void k_inorm_prelu(void* __restrict__ x, int f, int HW,
                              const void* __restrict__ a, const int* __restrict__ dmode)
{
  int dm = *dmode;
  long base = (long)blockIdx.x * HW;
  float s = 0.f, s2 = 0.f;
  int vec = (f == 0) && ((HW & 3) == 0);
  if(vec){
    const ushort4* vp = (const ushort4*)((const bf16*)x + base);
    int n = HW >> 2;
    for(int i = threadIdx.x; i < n; i += 256){
      ushort4 v = vp[i];
      float a0 = bfu(v.x), a1 = bfu(v.y), a2 = bfu(v.z), a3 = bfu(v.w);
      s  += (a0 + a1) + (a2 + a3);
      s2 += (a0*a0 + a1*a1) + (a2*a2 + a3*a3);
    }
  } else {
    for(int i = threadIdx.x; i < HW; i += 256){ float v = ldm(x, base + i, f); s += v; s2 += v*v; }
  }
  __shared__ float sh[256], sh2[256];
  sh[threadIdx.x] = s; sh2[threadIdx.x] = s2; __syncthreads();
  for(int off = 128; off > 0; off >>= 1){
    if(threadIdx.x < off){ sh[threadIdx.x] += sh[threadIdx.x+off]; sh2[threadIdx.x] += sh2[threadIdx.x+off]; }
    __syncthreads();
  }
  float mean = sh[0] / HW;
  float var  = sh2[0] / HW - mean * mean;
  float inv  = rsqrtf(fmaxf(var, 0.f) + 1e-5f);
  float alpha = ldm(a, 0, dm);
  if(vec){
    ushort4* vp = (ushort4*)((bf16*)x + base);
    int n = HW >> 2;
    for(int i = threadIdx.x; i < n; i += 256){
      ushort4 v = vp[i];
      float t[4] = { bfu(v.x), bfu(v.y), bfu(v.z), bfu(v.w) };
      #pragma unroll
      for(int k = 0; k < 4; k++){
        float u = (t[k] - mean) * inv;
        t[k] = u >= 0.f ? u : alpha * u;
      }
      ushort4 o;
      o.x = bfbits(t[0]); o.y = bfbits(t[1]); o.z = bfbits(t[2]); o.w = bfbits(t[3]);
      vp[i] = o;
    }
  } else {
    for(int i = threadIdx.x; i < HW; i += 256){
      float v = (ldm(x, base + i, f) - mean) * inv;
      stm(x, base + i, f, v >= 0.f ? v : alpha * v);
    }
  }
}

// ---------------- transpose [B,C,N] -> [B,N,C] (fp32) ----------------
__global__ void k_transpose(const float* __restrict__ in, float* __restrict__ out, int B, int C, int N){
  long idx = (long)blockIdx.x * 256 + threadIdx.x;
  long total = (long)B * C * N; if(idx >= total) return;
  int c = (int)(idx % C); long t = idx / C; int n = (int)(t % N); int b = (int)(t / N);
  out[idx] = in[((long)b * C + c) * N + n];
}

// ---------------- degree ----------------
__global__ void k_deg(const int* __restrict__ tgt, float* __restrict__ deg, int E){
  int e = blockIdx.x * 256 + threadIdx.x;
  if(e < E) atomicAdd(&deg[tgt[e]], 1.0f);
}

// ---------------- scatter add: agg[b,tgt,c] += x[b,src,c]  ([B,N,C] fp32) ----------------
__global__ void k_scatter(const float* __restrict__ xT, const int* __restrict__ src,
                          const int* __restrict__ tgt, float* __restrict__ agg,
                          int E, int C, int N, int B)
{
  int t = blockIdx.x * 256 + threadIdx.x;
  if(t >= E * C) return;
  int c = t % C; int e = t / C;
  int s = src[e], d = tgt[e];
  for(int b = 0; b < B; b++){
    atomicAdd(&agg[((long)b * N + d) * C + c], xT[((long)b * N + s) * C + c]);
  }
}

// ---------------- SAGE as MFMA GEMM ----------------
__global__ __launch_bounds__(256, 4)
void k_sageM(const float* __restrict__ xT, const float* __restrict__ agg,
             const float* __restrict__ deg,
             const bf16* __restrict__ wlF, const bf16* __restrict__ wrF,
             const void* __restrict__ bl,
             float* __restrict__ out, const int* __restrict__ dmode,
             int NROW, int trans)
{
  constexpr int CP = 264;                 // 528B rows: 16B aligned, 4-way max conflict
  __shared__ unsigned short sS[2*32*CP];
  int tid  = threadIdx.x;
  int lane = tid & 63;
  int wv   = tid >> 6;                    // wave = local o-chunk
  int ln   = lane & 31;
  int hi   = lane >> 5;
  int n0   = blockIdx.x * 32;
  int og0  = blockIdx.y * 128;
  int ncg  = blockIdx.y*4 + wv;           // global o-chunk (0..7)
  int dm   = *dmode;

  for(int e = tid; e < 4096; e += 256){
    int c4 = e & 63;
    int r  = (e >> 6) & 31;
    int ar = e >> 11;
    int row = n0 + r;
    unsigned pk0 = 0, pk1 = 0;
    if(row < NROW){
      const float* sp = ar ? agg : xT;
      float4 v = *(const float4*)&sp[(long)row*256 + c4*4];
      if(ar){
        int n = row % 625;
        float dinv = 1.0f / fmaxf(deg[n], 1.0f);
        v.x *= dinv; v.y *= dinv; v.z *= dinv; v.w *= dinv;
      }
      pk0 = bfbits(v.x) | ((unsigned)bfbits(v.y) << 16);
      pk1 = bfbits(v.z) | ((unsigned)bfbits(v.w) << 16);
    }
    uint2 q; q.x = pk0; q.y = pk1;
    *(uint2*)&sS[(ar*32 + r)*CP + c4*4] = q;
  }
  __syncthreads();

  f32x16 acc;
  #pragma unroll
  for(int q = 0; q < 16; q++) acc[q] = 0.f;

  int xb = ln*CP + 8*hi;
  #pragma unroll
  for(int kc = 0; kc < 16; kc++){
    bf16x8 bx = *(const bf16x8*)&sS[xb + kc*16];
    bf16x8 ba = *(const bf16x8*)&sS[32*CP + xb + kc*16];
    bf16x8 wl = ((const bf16x8*)wlF)[(long)(kc*8 + ncg)*64 + lane];
    bf16x8 wr = ((const bf16x8*)wrF)[(long)(kc*8 + ncg)*64 + lane];
    acc = __builtin_amdgcn_mfma_f32_32x32x16_bf16(wl, ba, acc, 0,0,0);
    acc = __builtin_amdgcn_mfma_f32_32x32x16_bf16(wr, bx, acc, 0,0,0);
  }

  if(trans){
    int row = n0 + ln;
    if(row < NROW){
      int b = row / 625, n = row - b*625;
      #pragma unroll
      for(int r16 = 0; r16 < 16; r16++){
        int o = ncg*32 + (r16&3) + 8*(r16>>2) + 4*hi;
        float v = acc[r16] + ldm(bl, o, dm);
        out[((long)b*256 + o)*625 + n] = fmaxf(v, 0.f);
      }
    }
  } else {
    float* sO = (float*)sS;               // reuse staging LDS (16.6KB <= 33.8KB)
    __syncthreads();
    #pragma unroll
    for(int r16 = 0; r16 < 16; r16++){
      int ol = wv*32 + (r16&3) + 8*(r16>>2) + 4*hi;   // o - og0
      float v = acc[r16] + ldm(bl, og0 + ol, dm);
      sO[ln*130 + ol] = fmaxf(v, 0.f);
    }
    __syncthreads();
    for(int e = tid; e < 4096; e += 256){
      int r = e >> 7, oc = e & 127;
      int row = n0 + r;
      if(row < NROW) out[(long)row*256 + og0 + oc] = sO[r*130 + oc];
    }
  }
}

// ---------------- ConvTranspose2d k=3 s=2 p=1 op=1 — MFMA, full-half staging ----------------
// r11: convTM's 16x (stage+barrier+18 MFMA+barrier) loop on u1's tiny 400-block
// grid ran 87% idle (MfmaUtil 6.5, Occ 14.6). Cin splits exactly into the two
// concat sources (C1==C2==CC): stage each CC-ch half ONCE (burst of ~68
// independent loads/thread), then run the half's whole K-sweep barrier-free.
// 32 barriers -> 4. LDS [row][col][ci], CIP=CC+8 (16B-aligned, 4-way max).
// MFMA math + store verbatim from the verified convTM.
template<int CW, int NWC, int CC, int CIP, int OCC>
__global__ __launch_bounds__(256, OCC)
void k_convTF(const void* __restrict__ inA, int fA,
              const void* __restrict__ inB, int fB,
              const bf16* __restrict__ wF, const void* __restrict__ bias,
              bf16* __restrict__ out, const int* __restrict__ dmode,
              int Hin, int Win, int Cout)
{
  __shared__ unsigned short sX[2*CW*CIP];
  int tid  = threadIdx.x;
  int lane = tid & 63;
  int wv   = tid >> 6;
  int nc   = wv % NWC;                // co-chunk of this wave
  int mt   = wv / NWC;                // col-tile of this wave
  int j0   = mt * 32;
  int i    = blockIdx.x;              // input row
  int b    = blockIdx.z;
  int dm   = *dmode;
  int ln   = lane & 31;
  int hi   = lane >> 5;
  int NCtot = Cout >> 5;

  f32x16 acc0, acc1, acc2, acc3;
  #pragma unroll
  for(int q = 0; q < 16; q++){ acc0[q]=0.f; acc1[q]=0.f; acc2[q]=0.f; acc3[q]=0.f; }

  #pragma unroll
  for(int half = 0; half < 2; half++){
    const void* sp = half ? inB : inA;
    int ff = half ? fB : fA;
    // ---- stage CC channels x 2 rows x CW cols -> [row][col][ci] ----
    for(int e = tid; e < 2*CW*(CC/8); e += 256){
      int col = e % CW;
      int s   = e / CW;
      int kg  = s % (CC/8);
      int row = s / (CC/8);
      int ii  = i + row;
      unsigned pk0=0, pk1=0, pk2=0, pk3=0;
      if(ii < Hin && col < Win){
        long step = (long)Hin*Win;
        long base = ((long)b*CC + kg*8)*step + (long)ii*Win + col;
        unsigned short t8[8];
        #pragma unroll
        for(int u = 0; u < 8; u++) t8[u] = bfbits(ldm(sp, base + u*step, ff));
        pk0 = t8[0] | ((unsigned)t8[1]<<16);
        pk1 = t8[2] | ((unsigned)t8[3]<<16);
        pk2 = t8[4] | ((unsigned)t8[5]<<16);
        pk3 = t8[6] | ((unsigned)t8[7]<<16);
      }
      uint4 q; q.x=pk0; q.y=pk1; q.z=pk2; q.w=pk3;
      *(uint4*)&sX[(row*CW + col)*CIP + kg*8] = q;
    }
    __syncthreads();

    // ---- barrier-free K-sweep over this half ----
    for(int kc = 0; kc < CC/16; kc++){
      int kb = kc*16 + 8*hi;
      bf16x8 x00 = *(const bf16x8*)&sX[(j0 + ln)*CIP + kb];
      bf16x8 x01 = *(const bf16x8*)&sX[(j0 + ln + 1)*CIP + kb];
      bf16x8 x10 = *(const bf16x8*)&sX[(CW + j0 + ln)*CIP + kb];
      bf16x8 x11 = *(const bf16x8*)&sX[(CW + j0 + ln + 1)*CIP + kb];
      int kcg = half*(CC/16) + kc;
      const bf16x8* wb = ((const bf16x8*)wF) + ((long)(kcg*9)*NCtot + nc)*64 + lane;
      const int ws = NCtot*64;
      bf16x8 w0=wb[0],    w1=wb[ws],   w2=wb[2*ws], w3=wb[3*ws], w4=wb[4*ws],
             w5=wb[5*ws], w6=wb[6*ws], w7=wb[7*ws], w8=wb[8*ws];
      acc0 = __builtin_amdgcn_mfma_f32_32x32x16_bf16(w4, x00, acc0, 0,0,0);
      acc1 = __builtin_amdgcn_mfma_f32_32x32x16_bf16(w5, x00, acc1, 0,0,0);
      acc1 = __builtin_amdgcn_mfma_f32_32x32x16_bf16(w3, x01, acc1, 0,0,0);
      acc2 = __builtin_amdgcn_mfma_f32_32x32x16_bf16(w7, x00, acc2, 0,0,0);
      acc2 = __builtin_amdgcn_mfma_f32_32x32x16_bf16(w1, x10, acc2, 0,0,0);
      acc3 = __builtin_amdgcn_mfma_f32_32x32x16_bf16(w8, x00, acc3, 0,0,0);
      acc3 = __builtin_amdgcn_mfma_f32_32x32x16_bf16(w6, x01, acc3, 0,0,0);
      acc3 = __builtin_amdgcn_mfma_f32_32x32x16_bf16(w2, x10, acc3, 0,0,0);
      acc3 = __builtin_amdgcn_mfma_f32_32x32x16_bf16(w0, x11, acc3, 0,0,0);
    }
    __syncthreads();
  }

  // ---- store: pack (pj=0,pj=1) as one 4B write, coalesced over lanes ----
  int j = j0 + ln;
  if(j < Win){
    int Wout = 2*Win;
    #pragma unroll
    for(int r = 0; r < 16; r++){
      int co = nc*32 + (r&3) + 8*(r>>2) + 4*hi;
      float bv = ldm(bias, co, dm);
      long base0 = (((long)b*Cout + co)*2*Hin + 2*i)*(long)Wout + 2*j;
      unsigned p0 = bfbits(acc0[r]+bv) | ((unsigned)bfbits(acc1[r]+bv) << 16);
      unsigned p1 = bfbits(acc2[r]+bv) | ((unsigned)bfbits(acc3[r]+bv) << 16);
      *(unsigned*)&out[base0]        = p0;
      *(unsigned*)&out[base0 + Wout] = p1;
    }
  }
}

// ---------------- u4 head: Cout=2, 4 px/thread, vectorized bf16 loads ----------------
__global__ __launch_bounds__(256, 2)
void k_convT8(const bf16* __restrict__ inA, const bf16* __restrict__ inB,
              const void* __restrict__ w, const void* __restrict__ bias,
              void* __restrict__ out, long out_off, int fout_sel,
              const int* __restrict__ dmode, int Hin, int Win)
{
  __shared__ float sW[64*2*9];
  __shared__ float sB[2];
  int tid = threadIdx.x;
  int dm = *dmode;
  for(int e = tid; e < 64*2*9; e += 256) sW[e] = ldm(w, e, dm);
  if(tid < 2) sB[tid] = ldm(bias, tid, dm);
  __syncthreads();
  int r  = tid / 50;                 // 0..4 rows per block (6 threads idle)
  int jt = tid % 50;
  if(r >= 5) return;
  int i  = blockIdx.x * 5 + r;
  int b  = blockIdx.z;
  int j0 = jt * 4;
  int fout = (fout_sel == 2) ? dm : fout_sel;

  float acc[2][4][4];
  #pragma unroll
  for(int co = 0; co < 2; co++)
    #pragma unroll
    for(int p = 0; p < 4; p++){
      acc[co][p][0]=0.f; acc[co][p][1]=0.f; acc[co][p][2]=0.f; acc[co][p][3]=0.f;
    }

  bool e4   = (j0 + 4 < Win);
  bool row1 = (i + 1 < Hin);

  for(int ci = 0; ci < 64; ci++){
    const bf16* src = (ci < 32) ? inA : inB;
    int cc = ci & 31;
    const bf16* rp = src + ((long)b*32 + cc)*(long)Hin*Win + (long)i*Win + j0;
    float x0[5], x1[5];
    ushort4 v0 = *(const ushort4*)rp;          // 8B aligned: j0 % 4 == 0
    x0[0]=bfu(v0.x); x0[1]=bfu(v0.y); x0[2]=bfu(v0.z); x0[3]=bfu(v0.w);
    x0[4] = e4 ? bf(rp[4]) : 0.f;
    if(row1){
      ushort4 v1 = *(const ushort4*)(rp + Win);
      x1[0]=bfu(v1.x); x1[1]=bfu(v1.y); x1[2]=bfu(v1.z); x1[3]=bfu(v1.w);
      x1[4] = e4 ? bf(rp[Win + 4]) : 0.f;
    } else {
      x1[0]=0.f; x1[1]=0.f; x1[2]=0.f; x1[3]=0.f; x1[4]=0.f;
    }
    const float* wp = &sW[ci*18];
    float wv[18];
    #pragma unroll
    for(int k = 0; k < 18; k++) wv[k] = wp[k];
    #pragma unroll
    for(int p = 0; p < 4; p++){
      float a00 = x0[p], a01 = x0[p+1], a10 = x1[p], a11 = x1[p+1];
      #pragma unroll
      for(int co = 0; co < 2; co++){
        const float* wc = &wv[co*9];
        acc[co][p][0] += a00*wc[4];
        acc[co][p][1] += a00*wc[5] + a01*wc[3];
        acc[co][p][2] += a00*wc[7] + a10*wc[1];
        acc[co][p][3] += a00*wc[8] + a01*wc[6] + a10*wc[2] + a11*wc[0];
      }
    }
  }
  int Wout = 2*Win;
  #pragma unroll
  for(int co = 0; co < 2; co++){
    float bv = sB[co];
    long base = out_off + (((long)b*2 + co)*2*Hin + 2*i)*(long)Wout + 2*j0;
    #pragma unroll
    for(int p = 0; p < 4; p++){
      stm(out, base + 2*p,            fout, acc[co][p][0] + bv);
      stm(out, base + 2*p + 1,        fout, acc[co][p][1] + bv);
      stm(out, base + 2*p + Wout,     fout, acc[co][p][2] + bv);
      stm(out, base + 2*p + Wout + 1, fout, acc[co][p][3] + bv);
    }
  }
}

static inline int cdiv(long a, long b){ return (int)((a + b - 1) / b); }

extern "C" void kernel_launch(void* const* d_in, const int* in_sizes, int n_in,
                              void* d_out, int out_size, void* d_ws, size_t ws_size,
                              hipStream_t stream) {
  const void* x_in  = d_in[0];
  const int*  edges = (const int*)d_in[1];
  const int* src = edges;          // edges[0,:]
  const int* tgt = edges + 5000;   // edges[1,:]
  const void *w_d4=d_in[2],  *b_d4=d_in[3],  *a_d4=d_in[4];
  const void *w_d3=d_in[5],  *b_d3=d_in[6],  *a_d3=d_in[7];
  const void *w_d2=d_in[8],  *b_d2=d_in[9],  *a_d2=d_in[10];
  const void *w_d1=d_in[11], *b_d1=d_in[12], *a_d1=d_in[13];
  const void *w_bot=d_in[14],*b_bot=d_in[15],*a_bot=d_in[16];
  const void *wl1=d_in[17], *bl1=d_in[18], *wr1=d_in[19];
  const void *wl2=d_in[20], *bl2=d_in[21], *wr2=d_in[22];
  const void *w_u1=d_in[23], *b_u1=d_in[24], *a_u1=d_in[25];
  const void *w_u2=d_in[26], *b_u2=d_in[27], *a_u2=d_in[28];
  const void *w_u3=d_in[29], *b_u3=d_in[30], *a_u3=d_in[31];
  const void *w_u4=d_in[32], *b_u4=d_in[33];

  const int NNODE = 625, E = 5000, CG = 256;

  // tail: deg/mode (4KB) + 4 sage wF bf16 (512KB, in old 1MB slot) + convT wF bf16
  const long TAIL = 4096 + 4*262144L + (589824L + 147456L + 36864L) * 2;
  // encoder wF (bf16): d3 18432 + d2 73728 + d1 294912 + bot 589824 = 976896 el
  const long ENCW = 976896L * 2;
  int Bc = 16;
  while(Bc > 1 && (7680000L * Bc + TAIL) > (long)ws_size) Bc >>= 1;
  int enc_in_pool = (Bc >= 8);   // pool free-gap holds 320000*Bc bytes >= ENCW iff Bc>=8
  if(!enc_in_pool){
    Bc = 16;
    while(Bc > 1 && (7680000L * Bc + TAIL + ENCW) > (long)ws_size) Bc >>= 1;
  }

  char* wsb = (char*)d_ws;
  long o_xs1  = 2560000L * Bc;
  long o_BIGA = 3840000L * Bc;
  long o_BIGB = 6400000L * Bc;
  long o_deg  = 7680000L * Bc;
  bf16*  xs0 = (bf16*)wsb;                             // [d4 -> u4]
  bf16*  xs1 = (bf16*)(wsb + o_xs1);                   // [d3 -> u3]
  bf16*  xs2 = (bf16*)(wsb + o_BIGA);                  // [d2 -> u2]
  bf16*  xs3 = (bf16*)(wsb + o_BIGA +  640000L*Bc);    // [d1 -> u1]
  float* bot = (float*)(wsb + o_BIGA +  960000L*Bc);   // [bot -> u1] (=g2)
  float* xT  = (float*)(wsb + o_BIGA + 1600000L*Bc);   // [tr -> sage1]
  bf16*  u1  = (bf16*)(wsb + o_BIGA + 1600000L*Bc);    // alias xT (dead)
  bf16*  u3  = (bf16*)(wsb + o_BIGA);                  // alias BIGA (dead)
  float* agg = (float*)(wsb + o_BIGB);
  float* g1  = (float*)(wsb + o_BIGB +  640000L*Bc);   // [sage1 -> sage2]
  bf16*  u2  = (bf16*)(wsb + o_BIGB);                  // alias agg+g1 (dead)
  float* deg = (float*)(wsb + o_deg);                  // 625 fp32
  int*  mode = (int*)(wsb + o_deg + 3072);
  bf16*  wlF1 = (bf16*)(wsb + o_deg + 4096);           // 4 x 65536 bf16 MFMA frags
  bf16*  wrF1 = wlF1 + 65536;
  bf16*  wlF2 = wrF1 + 65536;
  bf16*  wrF2 = wlF2 + 65536;
  bf16*  wTu1 = (bf16*)(wsb + o_deg + 4096 + 4*262144L); // 512*128*9 bf16 (frag order)
  bf16*  wTu2 = wTu1 + 589824;                         // 256*64*9
  bf16*  wTu3 = wTu2 + 147456;                         // 128*32*9
  // encoder weights: pool free-gap [BIGA+2240000*Bc, BIGA+2560000*Bc) when Bc>=8
  bf16*  wTd3 = enc_in_pool ? (bf16*)(wsb + o_BIGA + 2240000L*Bc) : (wTu3 + 36864);
  bf16*  wTd2 = wTd3 + 18432;
  bf16*  wTd1 = wTd2 + 73728;
  bf16*  wTdB = wTd1 + 294912;
  float* g2  = bot;

  hipLaunchKernelGGL(k_detect, dim3(1), dim3(1), 0, stream, w_d4, mode);

  hipMemsetAsync(deg, 0, NNODE*sizeof(float), stream);
  hipLaunchKernelGGL(k_deg, dim3(cdiv(E,256)), dim3(256), 0, stream, tgt, deg, E);
  hipLaunchKernelGGL(k_wtrans6, dim3(256), dim3(256), 0, stream, wl1, wlF1, mode);
  hipLaunchKernelGGL(k_wtrans6, dim3(256), dim3(256), 0, stream, wr1, wrF1, mode);
  hipLaunchKernelGGL(k_wtrans6, dim3(256), dim3(256), 0, stream, wl2, wlF2, mode);
  hipLaunchKernelGGL(k_wtrans6, dim3(256), dim3(256), 0, stream, wr2, wrF2, mode);
  hipLaunchKernelGGL(k_wtrans4, dim3(cdiv(589824,256)), dim3(256), 0, stream, w_u1, wTu1, mode, 512, 128);
  hipLaunchKernelGGL(k_wtrans4, dim3(cdiv(147456,256)), dim3(256), 0, stream, w_u2, wTu2, mode, 256, 64);
  hipLaunchKernelGGL(k_wtrans4, dim3(cdiv(36864,256)),  dim3(256), 0, stream, w_u3, wTu3, mode, 128, 32);

  for(int bo = 0; bo < 16; bo += Bc){
    long x_off   = (long)bo * 160000;
    long out_off = (long)bo * 320000;

    // encoder weight transposes (pool region may be clobbered by decoder -> per chunk)
    hipLaunchKernelGGL(k_wtrans5, dim3(cdiv(18432,256)),  dim3(256), 0, stream, w_d3, wTd3, mode, 32, 64);
    hipLaunchKernelGGL(k_wtrans5, dim3(cdiv(73728,256)),  dim3(256), 0, stream, w_d2, wTd2, mode, 64, 128);
    hipLaunchKernelGGL(k_wtrans5, dim3(cdiv(294912,256)), dim3(256), 0, stream, w_d1, wTd1, mode, 128, 256);
    hipLaunchKernelGGL(k_wtrans5, dim3(cdiv(589824,256)), dim3(256), 0, stream, w_bot, wTdB, mode, 256, 256);

    // ---- encoder: d4 dedicated coalesced kernel, d3/d2/d1/bot MFMA ----
    hipLaunchKernelGGL(k_conv_d4, dim3(40, 1, Bc), dim3(256), 0, stream,
                       x_in, x_off, w_d4, b_d4, xs0, mode);
    hipLaunchKernelGGL(k_inorm_prelu, dim3(Bc*32), dim3(256), 0, stream, xs0, 0, 40000, a_d4, mode);
    hipLaunchKernelGGL((k_convSM<130,2,2,2,4>), dim3(100, 2, Bc), dim3(256), 0, stream,
                       xs0, 0L, 0, wTd3, b_d3, xs1, 0, mode, 32, 200, 200, 64, 100, 100, 2);
    hipLaunchKernelGGL(k_inorm_prelu, dim3(Bc*64), dim3(256), 0, stream, xs1, 0, 10000, a_d3, mode);
    hipLaunchKernelGGL((k_convSM<66,4,1,2,4>), dim3(50, 2, Bc), dim3(256), 0, stream,
                       xs1, 0L, 0, wTd2, b_d2, xs2, 0, mode, 64, 100, 100, 128, 50, 50, 2);
    hipLaunchKernelGGL(k_inorm_prelu, dim3(Bc*128), dim3(256), 0, stream, xs2, 0, 2500, a_d2, mode);
    hipLaunchKernelGGL((k_convSM<66,4,1,2,4>), dim3(25, 2, Bc), dim3(256), 0, stream,
                       xs2, 0L, 0, wTd1, b_d1, xs3, 0, mode, 128, 50, 50, 256, 25, 25, 1);
    hipLaunchKernelGGL(k_inorm_prelu, dim3(Bc*256), dim3(256), 0, stream, xs3, 0, 625, a_d1, mode);
    hipLaunchKernelGGL((k_convSM<34,4,1,1,4>), dim3(25, 2, Bc), dim3(256), 0, stream,
                       xs3, 0L, 0, wTdB, b_bot, bot, 1, mode, 256, 25, 25, 256, 25, 25, 1);
    hipLaunchKernelGGL(k_inorm_prelu, dim3(Bc*256), dim3(256), 0, stream, bot, 1, 625, a_bot, mode);

    // ---- GNN ----
    { long n = (long)Bc*CG*NNODE;
      hipLaunchKernelGGL(k_transpose, dim3(cdiv(n,256)), dim3(256), 0, stream, bot, xT, Bc, CG, NNODE); }
    hipMemsetAsync(agg, 0, 640000L*Bc, stream);
    hipLaunchKernelGGL(k_scatter, dim3(cdiv((long)E*CG,256)), dim3(256), 0, stream, xT, src, tgt, agg, E, CG, NNODE, Bc);
    hipLaunchKernelGGL(k_sageM, dim3(cdiv((long)Bc*NNODE,32), 2), dim3(256), 0, stream,
                       xT, agg, deg, wlF1, wrF1, bl1, g1, mode, Bc*NNODE, 0);
    hipMemsetAsync(agg, 0, 640000L*Bc, stream);
    hipLaunchKernelGGL(k_scatter, dim3(cdiv((long)E*CG,256)), dim3(256), 0, stream, g1, src, tgt, agg, E, CG, NNODE, Bc);
    hipLaunchKernelGGL(k_sageM, dim3(cdiv((long)Bc*NNODE,32), 2), dim3(256), 0, stream,
                       g1, agg, deg, wlF2, wrF2, bl2, g2, mode, Bc*NNODE, 1);

    // ---- decoder (full-half-staged MFMA convT) ----
    // u1: C1=C2=256 (xs3 bf16 + g2 fp32), NWC=4, CW=34, LDS 35.9KB, OCC4
    hipLaunchKernelGGL((k_convTF<34,4,256,264,4>), dim3(25, 1, Bc), dim3(256), 0, stream,
                       xs3, 0, g2, 1, wTu1, b_u1, u1, mode, 25, 25, 128);
    hipLaunchKernelGGL(k_inorm_prelu, dim3(Bc*128), dim3(256), 0, stream, u1, 0, 2500, a_u1, mode);
    // u2: C1=C2=128, NWC=2 x 2 col-tiles, CW=66, LDS 35.9KB, OCC4
    hipLaunchKernelGGL((k_convTF<66,2,128,136,4>), dim3(50, 1, Bc), dim3(256), 0, stream,
                       xs2, 0, u1, 0, wTu2, b_u2, u2, mode, 50, 50, 64);
    hipLaunchKernelGGL(k_inorm_prelu, dim3(Bc*64), dim3(256), 0, stream, u2, 0, 10000, a_u2, mode);
    // u3: C1=C2=64, NWC=1 x 4 col-tiles, CW=130, LDS 37.4KB, OCC4
    hipLaunchKernelGGL((k_convTF<130,1,64,72,4>), dim3(100, 1, Bc), dim3(256), 0, stream,
                       xs1, 0, u2, 0, wTu3, b_u3, u3, mode, 100, 100, 32);
    hipLaunchKernelGGL(k_inorm_prelu, dim3(Bc*32), dim3(256), 0, stream, u3, 0, 40000, a_u3, mode);
    // u4: vectorized VALU head
    hipLaunchKernelGGL(k_convT8, dim3(40, 1, Bc), dim3(256), 0, stream,
                       xs0, u3, w_u4, b_u4, d_out, out_off, 2, mode, 200, 200);
  }
}

// Round 13
// 883.629 us; speedup vs baseline: 1.0248x; 1.0248x over previous
//
#include <hip/hip_runtime.h>
#include <hip/hip_bf16.h>

typedef __hip_bfloat16 bf16;

typedef __bf16 bf16x8 __attribute__((ext_vector_type(8)));
typedef float  f32x16 __attribute__((ext_vector_type(16)));

static __device__ __forceinline__ float bf(const bf16 v){ return __bfloat162float(v); }
static __device__ __forceinline__ float bfu(unsigned short u){
  unsigned fw = ((unsigned)u) << 16; float v; __builtin_memcpy(&v, &fw, 4); return v;
}

// flag f: 0 = bf16, 1 = fp32
static __device__ __forceinline__ float ldm(const void* p, long i, int f){
  return f ? ((const float*)p)[i] : __bfloat162float(((const bf16*)p)[i]);
}
static __device__ __forceinline__ void stm(void* p, long i, int f, float v){
  if(f) ((float*)p)[i] = v; else ((bf16*)p)[i] = __float2bfloat16(v);
}
static __device__ __forceinline__ unsigned short bfbits(float v){
  __hip_bfloat16 h = __float2bfloat16(v);
  return *(unsigned short*)&h;
}

// ---------------- input dtype detector (bit-level correct) ----------------
__global__ void k_detect(const void* __restrict__ w, int* __restrict__ mode){
  if(blockIdx.x == 0 && threadIdx.x == 0){
    const unsigned int* u = (const unsigned int*)w;
    int saneLo = 0;
    for(int i = 0; i < 64; i++){
      unsigned short lo = (unsigned short)(u[i] & 0xFFFFu);
      unsigned int fw = ((unsigned int)lo) << 16;
      float v; __builtin_memcpy(&v, &fw, 4);
      float a = fabsf(v);
      if(a > 1e-7f && a < 100.f) saneLo++;
    }
    *mode = (saneLo >= 48) ? 0 : 1;   // 0 = bf16, 1 = fp32
  }
}

// ---------------- SAGE weights [o][c] (256x256) -> MFMA A-frag order, bf16 ----------------
__global__ void k_wtrans6(const void* __restrict__ w, bf16* __restrict__ wF,
                          const int* __restrict__ dmode){
  int idx = blockIdx.x * 256 + threadIdx.x;
  if(idx >= 65536) return;
  int dm = *dmode;
  int e = idx & 7;
  int L = (idx >> 3) & 63;
  int r = idx >> 9;
  int nc = r & 7;
  int kc = r >> 3;
  int o = nc*32 + (L & 31);
  int c = kc*16 + (L >> 5)*8 + e;
  wF[idx] = __float2bfloat16(ldm(w, (long)o*256 + c, dm));
}

// ---------------- convT weights [Cin,Cout,3,3] -> MFMA A-fragment order ----------------
__global__ void k_wtrans4(const void* __restrict__ w, bf16* __restrict__ wF,
                          const int* __restrict__ dmode, int Cin, int Cout){
  int idx = blockIdx.x * 256 + threadIdx.x;
  if(idx >= Cin * Cout * 9) return;
  int dm = *dmode;
  int e = idx & 7;
  int L = (idx >> 3) & 63;
  int r = idx >> 9;
  int NC = Cout >> 5;
  int nc = r % NC; r /= NC;
  int t  = r % 9;
  int kc = r / 9;
  int ci = kc*16 + (L>>5)*8 + e;
  int co = nc*32 + (L&31);
  wF[idx] = __float2bfloat16(ldm(w, ((long)ci*Cout + co)*9 + t, dm));
}

// ---------------- conv weights [Cout,Cin,3,3] -> MFMA A-fragment order ----------------
__global__ void k_wtrans5(const void* __restrict__ w, bf16* __restrict__ wF,
                          const int* __restrict__ dmode, int Cin, int Cout){
  int idx = blockIdx.x * 256 + threadIdx.x;
  if(idx >= Cin * Cout * 9) return;
  int dm = *dmode;
  int e = idx & 7;
  int L = (idx >> 3) & 63;
  int r = idx >> 9;
  int NC = Cout >> 5;
  int nc = r % NC; r /= NC;
  int t  = r % 9;
  int kc = r / 9;
  int ci = kc*16 + (L>>5)*8 + e;
  int co = nc*32 + (L&31);
  wF[idx] = __float2bfloat16(ldm(w, ((long)co*Cin + ci)*9 + t, dm));
}

// ---------------- d4: Cin=1 conv 3x3 s=2, j-fast coalesced writes ----------------
__global__ __launch_bounds__(256, 4)
void k_conv_d4(const void* __restrict__ in, long in_off,
               const void* __restrict__ w, const void* __restrict__ bias,
               bf16* __restrict__ out, const int* __restrict__ dmode)
{
  __shared__ float sW[288];
  __shared__ float sB[32];
  int tid = threadIdx.x;
  int dm = *dmode;
  for(int e = tid; e < 288; e += 256) sW[e] = ldm(w, e, dm);
  if(tid < 32)  sB[tid] = ldm(bias, tid, dm);
  __syncthreads();
  int r = tid / 50, jt = tid % 50;
  if(r >= 5) return;
  int ho = blockIdx.x * 5 + r;
  int b  = blockIdx.z;
  int j0 = jt * 4;

  float x[3][9];
  long ibase = in_off + (long)b * 160000;
  #pragma unroll
  for(int rr = 0; rr < 3; rr++){
    int ir = 2*ho - 1 + rr;
    if(ir < 0 || ir >= 400){
      #pragma unroll
      for(int c = 0; c < 9; c++) x[rr][c] = 0.f;
      continue;
    }
    long rb = ibase + (long)ir * 400;
    int c0 = 2*j0 - 1;
    #pragma unroll
    for(int c = 0; c < 9; c++){
      int ic = c0 + c;
      x[rr][c] = (ic >= 0 && ic < 400) ? ldm(in, rb + ic, dm) : 0.f;
    }
  }

  long obase = ((long)b * 32) * 40000 + (long)ho * 200 + j0;
  for(int co = 0; co < 32; co++){
    const float* wv = &sW[co*9];
    float bv = sB[co];
    float a[4];
    #pragma unroll
    for(int p = 0; p < 4; p++){
      float s = bv;
      #pragma unroll
      for(int kh = 0; kh < 3; kh++)
        #pragma unroll
        for(int kw = 0; kw < 3; kw++)
          s += x[kh][2*p + kw] * wv[kh*3 + kw];
      a[p] = s;
    }
    ushort4 pk;
    pk.x = bfbits(a[0]); pk.y = bfbits(a[1]); pk.z = bfbits(a[2]); pk.w = bfbits(a[3]);
    *(ushort4*)&out[obase + (long)co * 40000] = pk;
  }
}

// ---------------- Conv2d 3x3 stride-S — MFMA 32x32x16 ----------------
template<int CW, int NWC, int NWM, int S, int OCC>
__global__ __launch_bounds__(256, OCC)
void k_convSM(const void* __restrict__ in, long in_off, int fin_sel,
              const bf16* __restrict__ wF, const void* __restrict__ bias,
              void* __restrict__ out, int fout,
              const int* __restrict__ dmode,
              int Cin, int Hin, int Win, int Cout, int Hout, int Wout, int nym)
{
  constexpr int CP = 40;
  constexpr int HALF = CW/2;
  __shared__ unsigned short sX[3*CW*CP];
  int tid  = threadIdx.x;
  int lane = tid & 63;
  int wv   = tid >> 6;
  int nc   = wv % NWC;
  int mt   = wv / NWC;
  int ho   = blockIdx.x;
  int colg = blockIdx.y % nym;
  int cog  = blockIdx.y / nym;
  int b    = blockIdx.z;
  int dm   = *dmode;
  int fin  = (fin_sel == 2) ? dm : fin_sel;
  int NCtot = Cout >> 5;
  int chunk = cog*NWC + nc;
  int jl   = mt*32 + (lane & 31);
  int hi   = lane >> 5;
  int C0   = S*(colg*NWM*32);
  int ir0  = S*ho - 1;

  f32x16 acc;
  #pragma unroll
  for(int q = 0; q < 16; q++) acc[q] = 0.f;

  int p0, p1, p2;
  if(S == 2){ p0 = jl; p1 = HALF + jl; p2 = jl + 1; }
  else      { p0 = jl; p1 = jl + 1;    p2 = jl + 2; }

  for(int ci0 = 0; ci0 < Cin; ci0 += 32){
    for(int e = tid; e < 12*CW; e += 256){
      int c  = e % CW;
      int s  = e / CW;
      int kg = s & 3, r = s >> 2;
      int ir = ir0 + r;
      int ic = C0 - 1 + c;
      unsigned pk0, pk1, pk2, pk3;
      if(ir >= 0 && ir < Hin && ic >= 0 && ic < Win){
        long step = (long)Hin*Win;
        long base = in_off + ((long)b*Cin + ci0 + kg*8)*step + (long)ir*Win + ic;
        unsigned short t8[8];
        #pragma unroll
        for(int u = 0; u < 8; u++) t8[u] = bfbits(ldm(in, base + u*step, fin));
        pk0 = t8[0] | ((unsigned)t8[1]<<16);
        pk1 = t8[2] | ((unsigned)t8[3]<<16);
        pk2 = t8[4] | ((unsigned)t8[5]<<16);
        pk3 = t8[6] | ((unsigned)t8[7]<<16);
      } else { pk0=0; pk1=0; pk2=0; pk3=0; }
      int pos = (S == 2) ? ((c&1) ? HALF + (c>>1) : (c>>1)) : c;
      uint4 q; q.x=pk0; q.y=pk1; q.z=pk2; q.w=pk3;
      *(uint4*)&sX[(r*CW + pos)*CP + kg*8] = q;
    }
    __syncthreads();

    #pragma unroll
    for(int kg2 = 0; kg2 < 2; kg2++){
      int kbase = 8*hi + kg2*16;
      bf16x8 x[9];
      #pragma unroll
      for(int r = 0; r < 3; r++){
        x[r*3+0] = *(const bf16x8*)&sX[(r*CW + p0)*CP + kbase];
        x[r*3+1] = *(const bf16x8*)&sX[(r*CW + p1)*CP + kbase];
        x[r*3+2] = *(const bf16x8*)&sX[(r*CW + p2)*CP + kbase];
      }
      int kc = (ci0 >> 4) + kg2;
      const bf16x8* wb = ((const bf16x8*)wF) + ((long)(kc*9)*NCtot + chunk)*64 + lane;
      const long ws = (long)NCtot*64;
      #pragma unroll
      for(int t = 0; t < 9; t++){
        bf16x8 w = wb[(long)t*ws];
        acc = __builtin_amdgcn_mfma_f32_32x32x16_bf16(w, x[t], acc, 0,0,0);
      }
    }
    __syncthreads();
  }

  int j = colg*NWM*32 + jl;
  if(j < Wout){
    #pragma unroll
    for(int r16 = 0; r16 < 16; r16++){
      int co = chunk*32 + (r16&3) + 8*(r16>>2) + 4*hi;
      float bv = ldm(bias, co, dm);
      stm(out, ((long)b*Cout + co)*Hout*Wout + (long)ho*Wout + j, fout, acc[r16] + bv);
    }
  }
}

// ---------------- InstanceNorm (affine=False) + PReLU, in place ----------------
__global__ void k_inorm_prelu(void* __restrict__ x, int f, int HW,
                              const void* __restrict__ a, const int* __restrict__ dmode)
{
  int dm = *dmode;
  long base = (long)blockIdx.x * HW;
  float s = 0.f, s2 = 0.f;
  int vec = (f == 0) && ((HW & 3) == 0);
  if(vec){
    const ushort4* vp = (const ushort4*)((const bf16*)x + base);
    int n = HW >> 2;
    for(int i = threadIdx.x; i < n; i += 256){
      ushort4 v = vp[i];
      float a0 = bfu(v.x), a1 = bfu(v.y), a2 = bfu(v.z), a3 = bfu(v.w);
      s  += (a0 + a1) + (a2 + a3);
      s2 += (a0*a0 + a1*a1) + (a2*a2 + a3*a3);
    }
  } else {
    for(int i = threadIdx.x; i < HW; i += 256){ float v = ldm(x, base + i, f); s += v; s2 += v*v; }
  }
  __shared__ float sh[256], sh2[256];
  sh[threadIdx.x] = s; sh2[threadIdx.x] = s2; __syncthreads();
  for(int off = 128; off > 0; off >>= 1){
    if(threadIdx.x < off){ sh[threadIdx.x] += sh[threadIdx.x+off]; sh2[threadIdx.x] += sh2[threadIdx.x+off]; }
    __syncthreads();
  }
  float mean = sh[0] / HW;
  float var  = sh2[0] / HW - mean * mean;
  float inv  = rsqrtf(fmaxf(var, 0.f) + 1e-5f);
  float alpha = ldm(a, 0, dm);
  if(vec){
    ushort4* vp = (ushort4*)((bf16*)x + base);
    int n = HW >> 2;
    for(int i = threadIdx.x; i < n; i += 256){
      ushort4 v = vp[i];
      float t[4] = { bfu(v.x), bfu(v.y), bfu(v.z), bfu(v.w) };
      #pragma unroll
      for(int k = 0; k < 4; k++){
        float u = (t[k] - mean) * inv;
        t[k] = u >= 0.f ? u : alpha * u;
      }
      ushort4 o;
      o.x = bfbits(t[0]); o.y = bfbits(t[1]); o.z = bfbits(t[2]); o.w = bfbits(t[3]);
      vp[i] = o;
    }
  } else {
    for(int i = threadIdx.x; i < HW; i += 256){
      float v = (ldm(x, base + i, f) - mean) * inv;
      stm(x, base + i, f, v >= 0.f ? v : alpha * v);
    }
  }
}

// ---------------- transpose [B,C,N] -> [B,N,C] (fp32) ----------------
__global__ void k_transpose(const float* __restrict__ in, float* __restrict__ out, int B, int C, int N){
  long idx = (long)blockIdx.x * 256 + threadIdx.x;
  long total = (long)B * C * N; if(idx >= total) return;
  int c = (int)(idx % C); long t = idx / C; int n = (int)(t % N); int b = (int)(t / N);
  out[idx] = in[((long)b * C + c) * N + n];
}

// ---------------- degree ----------------
__global__ void k_deg(const int* __restrict__ tgt, float* __restrict__ deg, int E){
  int e = blockIdx.x * 256 + threadIdx.x;
  if(e < E) atomicAdd(&deg[tgt[e]], 1.0f);
}

// ---------------- scatter add: agg[b,tgt,c] += x[b,src,c]  ([B,N,C] fp32) ----------------
__global__ void k_scatter(const float* __restrict__ xT, const int* __restrict__ src,
                          const int* __restrict__ tgt, float* __restrict__ agg,
                          int E, int C, int N, int B)
{
  int t = blockIdx.x * 256 + threadIdx.x;
  if(t >= E * C) return;
  int c = t % C; int e = t / C;
  int s = src[e], d = tgt[e];
  for(int b = 0; b < B; b++){
    atomicAdd(&agg[((long)b * N + d) * C + c], xT[((long)b * N + s) * C + c]);
  }
}

// ---------------- SAGE as MFMA GEMM ----------------
__global__ __launch_bounds__(256, 4)
void k_sageM(const float* __restrict__ xT, const float* __restrict__ agg,
             const float* __restrict__ deg,
             const bf16* __restrict__ wlF, const bf16* __restrict__ wrF,
             const void* __restrict__ bl,
             float* __restrict__ out, const int* __restrict__ dmode,
             int NROW, int trans)
{
  constexpr int CP = 264;
  __shared__ unsigned short sS[2*32*CP];
  int tid  = threadIdx.x;
  int lane = tid & 63;
  int wv   = tid >> 6;
  int ln   = lane & 31;
  int hi   = lane >> 5;
  int n0   = blockIdx.x * 32;
  int og0  = blockIdx.y * 128;
  int ncg  = blockIdx.y*4 + wv;
  int dm   = *dmode;

  for(int e = tid; e < 4096; e += 256){
    int c4 = e & 63;
    int r  = (e >> 6) & 31;
    int ar = e >> 11;
    int row = n0 + r;
    unsigned pk0 = 0, pk1 = 0;
    if(row < NROW){
      const float* sp = ar ? agg : xT;
      float4 v = *(const float4*)&sp[(long)row*256 + c4*4];
      if(ar){
        int n = row % 625;
        float dinv = 1.0f / fmaxf(deg[n], 1.0f);
        v.x *= dinv; v.y *= dinv; v.z *= dinv; v.w *= dinv;
      }
      pk0 = bfbits(v.x) | ((unsigned)bfbits(v.y) << 16);
      pk1 = bfbits(v.z) | ((unsigned)bfbits(v.w) << 16);
    }
    uint2 q; q.x = pk0; q.y = pk1;
    *(uint2*)&sS[(ar*32 + r)*CP + c4*4] = q;
  }
  __syncthreads();

  f32x16 acc;
  #pragma unroll
  for(int q = 0; q < 16; q++) acc[q] = 0.f;

  int xb = ln*CP + 8*hi;
  #pragma unroll
  for(int kc = 0; kc < 16; kc++){
    bf16x8 bx = *(const bf16x8*)&sS[xb + kc*16];
    bf16x8 ba = *(const bf16x8*)&sS[32*CP + xb + kc*16];
    bf16x8 wl = ((const bf16x8*)wlF)[(long)(kc*8 + ncg)*64 + lane];
    bf16x8 wr = ((const bf16x8*)wrF)[(long)(kc*8 + ncg)*64 + lane];
    acc = __builtin_amdgcn_mfma_f32_32x32x16_bf16(wl, ba, acc, 0,0,0);
    acc = __builtin_amdgcn_mfma_f32_32x32x16_bf16(wr, bx, acc, 0,0,0);
  }

  if(trans){
    int row = n0 + ln;
    if(row < NROW){
      int b = row / 625, n = row - b*625;
      #pragma unroll
      for(int r16 = 0; r16 < 16; r16++){
        int o = ncg*32 + (r16&3) + 8*(r16>>2) + 4*hi;
        float v = acc[r16] + ldm(bl, o, dm);
        out[((long)b*256 + o)*625 + n] = fmaxf(v, 0.f);
      }
    }
  } else {
    float* sO = (float*)sS;
    __syncthreads();
    #pragma unroll
    for(int r16 = 0; r16 < 16; r16++){
      int ol = wv*32 + (r16&3) + 8*(r16>>2) + 4*hi;
      float v = acc[r16] + ldm(bl, og0 + ol, dm);
      sO[ln*130 + ol] = fmaxf(v, 0.f);
    }
    __syncthreads();
    for(int e = tid; e < 4096; e += 256){
      int r = e >> 7, oc = e & 127;
      int row = n0 + r;
      if(row < NROW) out[(long)row*256 + og0 + oc] = sO[r*130 + oc];
    }
  }
}

// ---------------- ConvTranspose2d — MFMA, in-block K-split (8 waves) ----------------
// r12: convTF (fewer barriers) left MfmaUtil at 6.4 / Occ 15.7 — the layers are
// GRID-bound (u1: 400 blocks x 4 waves = 6 waves/CU) with one serial K-chain
// per block. Fix: 512-thread blocks, 8 waves = 4 (nc x mt) x 2 K-halves; both
// concat halves staged at once; each wave sweeps its half (chain halved);
// cross-half combine via fp32 LDS bounce (idx-major, conflict-free); h=0 adds
// bias + stores (store verbatim from verified convTF). 2x waves/CU, 0 extra
// global traffic, 3 barriers.
template<int CW, int NWC, int NWM, int CC, int CIP>
__global__ __launch_bounds__(512, 4)
void k_convTG(const void* __restrict__ inA, int fA,
              const void* __restrict__ inB, int fB,
              const bf16* __restrict__ wF, const void* __restrict__ bias,
              bf16* __restrict__ out, const int* __restrict__ dmode,
              int Hin, int Win, int Cout)
{
  __shared__ unsigned short sX[4*CW*CIP];   // >= 64KB, doubles as fp32 sR[16384]
  int tid  = threadIdx.x;
  int lane = tid & 63;
  int wv   = tid >> 6;          // 0..7
  int low  = wv & 3;
  int h    = wv >> 2;           // K-half of this wave
  int nc   = low % NWC;
  int mt   = low / NWC;
  int j0   = mt * 32;
  int i    = blockIdx.x;
  int b    = blockIdx.z;
  int dm   = *dmode;
  int ln   = lane & 31;
  int hi   = lane >> 5;
  int NCtot = Cout >> 5;

  f32x16 acc0, acc1, acc2, acc3;
  #pragma unroll
  for(int q = 0; q < 16; q++){ acc0[q]=0.f; acc1[q]=0.f; acc2[q]=0.f; acc3[q]=0.f; }

  // ---- stage BOTH halves: 2 src x 2 rows x CW cols x CC ch -> [hf][row][col][ci] ----
  for(int e = tid; e < 4*CW*(CC/8); e += 512){
    int col = e % CW;
    int s   = e / CW;
    int kg  = s % (CC/8); s /= (CC/8);
    int row = s & 1;
    int hf  = s >> 1;
    int ii  = i + row;
    unsigned pk0=0, pk1=0, pk2=0, pk3=0;
    if(ii < Hin && col < Win){
      const void* sp = hf ? inB : inA;
      int ff = hf ? fB : fA;
      long step = (long)Hin*Win;
      long base = ((long)b*CC + kg*8)*step + (long)ii*Win + col;
      unsigned short t8[8];
      #pragma unroll
      for(int u = 0; u < 8; u++) t8[u] = bfbits(ldm(sp, base + u*step, ff));
      pk0 = t8[0] | ((unsigned)t8[1]<<16);
      pk1 = t8[2] | ((unsigned)t8[3]<<16);
      pk2 = t8[4] | ((unsigned)t8[5]<<16);
      pk3 = t8[6] | ((unsigned)t8[7]<<16);
    }
    uint4 q; q.x=pk0; q.y=pk1; q.z=pk2; q.w=pk3;
    *(uint4*)&sX[((hf*2 + row)*CW + col)*CIP + kg*8] = q;
  }
  __syncthreads();

  // ---- barrier-free K-sweep over this wave's half ----
  for(int kc = 0; kc < CC/16; kc++){
    int kb = kc*16 + 8*hi;
    bf16x8 x00 = *(const bf16x8*)&sX[((h*2+0)*CW + j0 + ln)*CIP + kb];
    bf16x8 x01 = *(const bf16x8*)&sX[((h*2+0)*CW + j0 + ln + 1)*CIP + kb];
    bf16x8 x10 = *(const bf16x8*)&sX[((h*2+1)*CW + j0 + ln)*CIP + kb];
    bf16x8 x11 = *(const bf16x8*)&sX[((h*2+1)*CW + j0 + ln + 1)*CIP + kb];
    int kcg = h*(CC/16) + kc;
    const bf16x8* wb = ((const bf16x8*)wF) + ((long)(kcg*9)*NCtot + nc)*64 + lane;
    const int ws = NCtot*64;
    bf16x8 w0=wb[0],    w1=wb[ws],   w2=wb[2*ws], w3=wb[3*ws], w4=wb[4*ws],
           w5=wb[5*ws], w6=wb[6*ws], w7=wb[7*ws], w8=wb[8*ws];
    acc0 = __builtin_amdgcn_mfma_f32_32x32x16_bf16(w4, x00, acc0, 0,0,0);
    acc1 = __builtin_amdgcn_mfma_f32_32x32x16_bf16(w5, x00, acc1, 0,0,0);
    acc1 = __builtin_amdgcn_mfma_f32_32x32x16_bf16(w3, x01, acc1, 0,0,0);
    acc2 = __builtin_amdgcn_mfma_f32_32x32x16_bf16(w7, x00, acc2, 0,0,0);
    acc2 = __builtin_amdgcn_mfma_f32_32x32x16_bf16(w1, x10, acc2, 0,0,0);
    acc3 = __builtin_amdgcn_mfma_f32_32x32x16_bf16(w8, x00, acc3, 0,0,0);
    acc3 = __builtin_amdgcn_mfma_f32_32x32x16_bf16(w6, x01, acc3, 0,0,0);
    acc3 = __builtin_amdgcn_mfma_f32_32x32x16_bf16(w2, x10, acc3, 0,0,0);
    acc3 = __builtin_amdgcn_mfma_f32_32x32x16_bf16(w0, x11, acc3, 0,0,0);
  }

  // ---- cross-half reduction via LDS (idx-major: lanes consecutive per idx) ----
  float* sR = (float*)sX;
  __syncthreads();                 // all waves done reading sX
  if(h == 1){
    #pragma unroll
    for(int q = 0; q < 16; q++){
      sR[(0*16+q)*256 + low*64 + lane] = acc0[q];
      sR[(1*16+q)*256 + low*64 + lane] = acc1[q];
      sR[(2*16+q)*256 + low*64 + lane] = acc2[q];
      sR[(3*16+q)*256 + low*64 + lane] = acc3[q];
    }
  }
  __syncthreads();
  if(h == 0){
    #pragma unroll
    for(int q = 0; q < 16; q++){
      acc0[q] += sR[(0*16+q)*256 + low*64 + lane];
      acc1[q] += sR[(1*16+q)*256 + low*64 + lane];
      acc2[q] += sR[(2*16+q)*256 + low*64 + lane];
      acc3[q] += sR[(3*16+q)*256 + low*64 + lane];
    }
    int j = j0 + ln;
    if(j < Win){
      int Wout = 2*Win;
      #pragma unroll
      for(int r = 0; r < 16; r++){
        int co = nc*32 + (r&3) + 8*(r>>2) + 4*hi;
        float bv = ldm(bias, co, dm);
        long base0 = (((long)b*Cout + co)*2*Hin + 2*i)*(long)Wout + 2*j;
        unsigned p0 = bfbits(acc0[r]+bv) | ((unsigned)bfbits(acc1[r]+bv) << 16);
        unsigned p1 = bfbits(acc2[r]+bv) | ((unsigned)bfbits(acc3[r]+bv) << 16);
        *(unsigned*)&out[base0]        = p0;
        *(unsigned*)&out[base0 + Wout] = p1;
      }
    }
  }
}

// ---------------- u4 head: Cout=2, 4 px/thread, vectorized bf16 loads ----------------
__global__ __launch_bounds__(256, 2)
void k_convT8(const bf16* __restrict__ inA, const bf16* __restrict__ inB,
              const void* __restrict__ w, const void* __restrict__ bias,
              void* __restrict__ out, long out_off, int fout_sel,
              const int* __restrict__ dmode, int Hin, int Win)
{
  __shared__ float sW[64*2*9];
  __shared__ float sB[2];
  int tid = threadIdx.x;
  int dm = *dmode;
  for(int e = tid; e < 64*2*9; e += 256) sW[e] = ldm(w, e, dm);
  if(tid < 2) sB[tid] = ldm(bias, tid, dm);
  __syncthreads();
  int r  = tid / 50;
  int jt = tid % 50;
  if(r >= 5) return;
  int i  = blockIdx.x * 5 + r;
  int b  = blockIdx.z;
  int j0 = jt * 4;
  int fout = (fout_sel == 2) ? dm : fout_sel;

  float acc[2][4][4];
  #pragma unroll
  for(int co = 0; co < 2; co++)
    #pragma unroll
    for(int p = 0; p < 4; p++){
      acc[co][p][0]=0.f; acc[co][p][1]=0.f; acc[co][p][2]=0.f; acc[co][p][3]=0.f;
    }

  bool e4   = (j0 + 4 < Win);
  bool row1 = (i + 1 < Hin);

  for(int ci = 0; ci < 64; ci++){
    const bf16* src = (ci < 32) ? inA : inB;
    int cc = ci & 31;
    const bf16* rp = src + ((long)b*32 + cc)*(long)Hin*Win + (long)i*Win + j0;
    float x0[5], x1[5];
    ushort4 v0 = *(const ushort4*)rp;
    x0[0]=bfu(v0.x); x0[1]=bfu(v0.y); x0[2]=bfu(v0.z); x0[3]=bfu(v0.w);
    x0[4] = e4 ? bf(rp[4]) : 0.f;
    if(row1){
      ushort4 v1 = *(const ushort4*)(rp + Win);
      x1[0]=bfu(v1.x); x1[1]=bfu(v1.y); x1[2]=bfu(v1.z); x1[3]=bfu(v1.w);
      x1[4] = e4 ? bf(rp[Win + 4]) : 0.f;
    } else {
      x1[0]=0.f; x1[1]=0.f; x1[2]=0.f; x1[3]=0.f; x1[4]=0.f;
    }
    const float* wp = &sW[ci*18];
    float wv[18];
    #pragma unroll
    for(int k = 0; k < 18; k++) wv[k] = wp[k];
    #pragma unroll
    for(int p = 0; p < 4; p++){
      float a00 = x0[p], a01 = x0[p+1], a10 = x1[p], a11 = x1[p+1];
      #pragma unroll
      for(int co = 0; co < 2; co++){
        const float* wc = &wv[co*9];
        acc[co][p][0] += a00*wc[4];
        acc[co][p][1] += a00*wc[5] + a01*wc[3];
        acc[co][p][2] += a00*wc[7] + a10*wc[1];
        acc[co][p][3] += a00*wc[8] + a01*wc[6] + a10*wc[2] + a11*wc[0];
      }
    }
  }
  int Wout = 2*Win;
  #pragma unroll
  for(int co = 0; co < 2; co++){
    float bv = sB[co];
    long base = out_off + (((long)b*2 + co)*2*Hin + 2*i)*(long)Wout + 2*j0;
    #pragma unroll
    for(int p = 0; p < 4; p++){
      stm(out, base + 2*p,            fout, acc[co][p][0] + bv);
      stm(out, base + 2*p + 1,        fout, acc[co][p][1] + bv);
      stm(out, base + 2*p + Wout,     fout, acc[co][p][2] + bv);
      stm(out, base + 2*p + Wout + 1, fout, acc[co][p][3] + bv);
    }
  }
}

static inline int cdiv(long a, long b){ return (int)((a + b - 1) / b); }

extern "C" void kernel_launch(void* const* d_in, const int* in_sizes, int n_in,
                              void* d_out, int out_size, void* d_ws, size_t ws_size,
                              hipStream_t stream) {
  const void* x_in  = d_in[0];
  const int*  edges = (const int*)d_in[1];
  const int* src = edges;          // edges[0,:]
  const int* tgt = edges + 5000;   // edges[1,:]
  const void *w_d4=d_in[2],  *b_d4=d_in[3],  *a_d4=d_in[4];
  const void *w_d3=d_in[5],  *b_d3=d_in[6],  *a_d3=d_in[7];
  const void *w_d2=d_in[8],  *b_d2=d_in[9],  *a_d2=d_in[10];
  const void *w_d1=d_in[11], *b_d1=d_in[12], *a_d1=d_in[13];
  const void *w_bot=d_in[14],*b_bot=d_in[15],*a_bot=d_in[16];
  const void *wl1=d_in[17], *bl1=d_in[18], *wr1=d_in[19];
  const void *wl2=d_in[20], *bl2=d_in[21], *wr2=d_in[22];
  const void *w_u1=d_in[23], *b_u1=d_in[24], *a_u1=d_in[25];
  const void *w_u2=d_in[26], *b_u2=d_in[27], *a_u2=d_in[28];
  const void *w_u3=d_in[29], *b_u3=d_in[30], *a_u3=d_in[31];
  const void *w_u4=d_in[32], *b_u4=d_in[33];

  const int NNODE = 625, E = 5000, CG = 256;

  // tail: deg/mode (4KB) + 4 sage wF bf16 (512KB, in old 1MB slot) + convT wF bf16
  const long TAIL = 4096 + 4*262144L + (589824L + 147456L + 36864L) * 2;
  // encoder wF (bf16): d3 18432 + d2 73728 + d1 294912 + bot 589824 = 976896 el
  const long ENCW = 976896L * 2;
  int Bc = 16;
  while(Bc > 1 && (7680000L * Bc + TAIL) > (long)ws_size) Bc >>= 1;
  int enc_in_pool = (Bc >= 8);   // pool free-gap holds 320000*Bc bytes >= ENCW iff Bc>=8
  if(!enc_in_pool){
    Bc = 16;
    while(Bc > 1 && (7680000L * Bc + TAIL + ENCW) > (long)ws_size) Bc >>= 1;
  }

  char* wsb = (char*)d_ws;
  long o_xs1  = 2560000L * Bc;
  long o_BIGA = 3840000L * Bc;
  long o_BIGB = 6400000L * Bc;
  long o_deg  = 7680000L * Bc;
  bf16*  xs0 = (bf16*)wsb;                             // [d4 -> u4]
  bf16*  xs1 = (bf16*)(wsb + o_xs1);                   // [d3 -> u3]
  bf16*  xs2 = (bf16*)(wsb + o_BIGA);                  // [d2 -> u2]
  bf16*  xs3 = (bf16*)(wsb + o_BIGA +  640000L*Bc);    // [d1 -> u1]
  float* bot = (float*)(wsb + o_BIGA +  960000L*Bc);   // [bot -> u1] (=g2)
  float* xT  = (float*)(wsb + o_BIGA + 1600000L*Bc);   // [tr -> sage1]
  bf16*  u1  = (bf16*)(wsb + o_BIGA + 1600000L*Bc);    // alias xT (dead)
  bf16*  u3  = (bf16*)(wsb + o_BIGA);                  // alias BIGA (dead)
  float* agg = (float*)(wsb + o_BIGB);
  float* g1  = (float*)(wsb + o_BIGB +  640000L*Bc);   // [sage1 -> sage2]
  bf16*  u2  = (bf16*)(wsb + o_BIGB);                  // alias agg+g1 (dead)
  float* deg = (float*)(wsb + o_deg);                  // 625 fp32
  int*  mode = (int*)(wsb + o_deg + 3072);
  bf16*  wlF1 = (bf16*)(wsb + o_deg + 4096);           // 4 x 65536 bf16 MFMA frags
  bf16*  wrF1 = wlF1 + 65536;
  bf16*  wlF2 = wrF1 + 65536;
  bf16*  wrF2 = wlF2 + 65536;
  bf16*  wTu1 = (bf16*)(wsb + o_deg + 4096 + 4*262144L); // 512*128*9 bf16 (frag order)
  bf16*  wTu2 = wTu1 + 589824;                         // 256*64*9
  bf16*  wTu3 = wTu2 + 147456;                         // 128*32*9
  // encoder weights: pool free-gap [BIGA+2240000*Bc, BIGA+2560000*Bc) when Bc>=8
  bf16*  wTd3 = enc_in_pool ? (bf16*)(wsb + o_BIGA + 2240000L*Bc) : (wTu3 + 36864);
  bf16*  wTd2 = wTd3 + 18432;
  bf16*  wTd1 = wTd2 + 73728;
  bf16*  wTdB = wTd1 + 294912;
  float* g2  = bot;

  hipLaunchKernelGGL(k_detect, dim3(1), dim3(1), 0, stream, w_d4, mode);

  hipMemsetAsync(deg, 0, NNODE*sizeof(float), stream);
  hipLaunchKernelGGL(k_deg, dim3(cdiv(E,256)), dim3(256), 0, stream, tgt, deg, E);
  hipLaunchKernelGGL(k_wtrans6, dim3(256), dim3(256), 0, stream, wl1, wlF1, mode);
  hipLaunchKernelGGL(k_wtrans6, dim3(256), dim3(256), 0, stream, wr1, wrF1, mode);
  hipLaunchKernelGGL(k_wtrans6, dim3(256), dim3(256), 0, stream, wl2, wlF2, mode);
  hipLaunchKernelGGL(k_wtrans6, dim3(256), dim3(256), 0, stream, wr2, wrF2, mode);
  hipLaunchKernelGGL(k_wtrans4, dim3(cdiv(589824,256)), dim3(256), 0, stream, w_u1, wTu1, mode, 512, 128);
  hipLaunchKernelGGL(k_wtrans4, dim3(cdiv(147456,256)), dim3(256), 0, stream, w_u2, wTu2, mode, 256, 64);
  hipLaunchKernelGGL(k_wtrans4, dim3(cdiv(36864,256)),  dim3(256), 0, stream, w_u3, wTu3, mode, 128, 32);

  for(int bo = 0; bo < 16; bo += Bc){
    long x_off   = (long)bo * 160000;
    long out_off = (long)bo * 320000;

    // encoder weight transposes (pool region may be clobbered by decoder -> per chunk)
    hipLaunchKernelGGL(k_wtrans5, dim3(cdiv(18432,256)),  dim3(256), 0, stream, w_d3, wTd3, mode, 32, 64);
    hipLaunchKernelGGL(k_wtrans5, dim3(cdiv(73728,256)),  dim3(256), 0, stream, w_d2, wTd2, mode, 64, 128);
    hipLaunchKernelGGL(k_wtrans5, dim3(cdiv(294912,256)), dim3(256), 0, stream, w_d1, wTd1, mode, 128, 256);
    hipLaunchKernelGGL(k_wtrans5, dim3(cdiv(589824,256)), dim3(256), 0, stream, w_bot, wTdB, mode, 256, 256);

    // ---- encoder: d4 dedicated coalesced kernel, d3/d2/d1/bot MFMA ----
    hipLaunchKernelGGL(k_conv_d4, dim3(40, 1, Bc), dim3(256), 0, stream,
                       x_in, x_off, w_d4, b_d4, xs0, mode);
    hipLaunchKernelGGL(k_inorm_prelu, dim3(Bc*32), dim3(256), 0, stream, xs0, 0, 40000, a_d4, mode);
    hipLaunchKernelGGL((k_convSM<130,2,2,2,4>), dim3(100, 2, Bc), dim3(256), 0, stream,
                       xs0, 0L, 0, wTd3, b_d3, xs1, 0, mode, 32, 200, 200, 64, 100, 100, 2);
    hipLaunchKernelGGL(k_inorm_prelu, dim3(Bc*64), dim3(256), 0, stream, xs1, 0, 10000, a_d3, mode);
    hipLaunchKernelGGL((k_convSM<66,4,1,2,4>), dim3(50, 2, Bc), dim3(256), 0, stream,
                       xs1, 0L, 0, wTd2, b_d2, xs2, 0, mode, 64, 100, 100, 128, 50, 50, 2);
    hipLaunchKernelGGL(k_inorm_prelu, dim3(Bc*128), dim3(256), 0, stream, xs2, 0, 2500, a_d2, mode);
    hipLaunchKernelGGL((k_convSM<66,4,1,2,4>), dim3(25, 2, Bc), dim3(256), 0, stream,
                       xs2, 0L, 0, wTd1, b_d1, xs3, 0, mode, 128, 50, 50, 256, 25, 25, 1);
    hipLaunchKernelGGL(k_inorm_prelu, dim3(Bc*256), dim3(256), 0, stream, xs3, 0, 625, a_d1, mode);
    hipLaunchKernelGGL((k_convSM<34,4,1,1,4>), dim3(25, 2, Bc), dim3(256), 0, stream,
                       xs3, 0L, 0, wTdB, b_bot, bot, 1, mode, 256, 25, 25, 256, 25, 25, 1);
    hipLaunchKernelGGL(k_inorm_prelu, dim3(Bc*256), dim3(256), 0, stream, bot, 1, 625, a_bot, mode);

    // ---- GNN ----
    { long n = (long)Bc*CG*NNODE;
      hipLaunchKernelGGL(k_transpose, dim3(cdiv(n,256)), dim3(256), 0, stream, bot, xT, Bc, CG, NNODE); }
    hipMemsetAsync(agg, 0, 640000L*Bc, stream);
    hipLaunchKernelGGL(k_scatter, dim3(cdiv((long)E*CG,256)), dim3(256), 0, stream, xT, src, tgt, agg, E, CG, NNODE, Bc);
    hipLaunchKernelGGL(k_sageM, dim3(cdiv((long)Bc*NNODE,32), 2), dim3(256), 0, stream,
                       xT, agg, deg, wlF1, wrF1, bl1, g1, mode, Bc*NNODE, 0);
    hipMemsetAsync(agg, 0, 640000L*Bc, stream);
    hipLaunchKernelGGL(k_scatter, dim3(cdiv((long)E*CG,256)), dim3(256), 0, stream, g1, src, tgt, agg, E, CG, NNODE, Bc);
    hipLaunchKernelGGL(k_sageM, dim3(cdiv((long)Bc*NNODE,32), 2), dim3(256), 0, stream,
                       g1, agg, deg, wlF2, wrF2, bl2, g2, mode, Bc*NNODE, 1);

    // ---- decoder (K-split 8-wave MFMA convT) ----
    // u1: C1=C2=256 (xs3 bf16 + g2 fp32), NWC=4 NWM=1, LDS 70.1KB (2/CU)
    hipLaunchKernelGGL((k_convTG<34,4,1,256,264>), dim3(25, 1, Bc), dim3(512), 0, stream,
                       xs3, 0, g2, 1, wTu1, b_u1, u1, mode, 25, 25, 128);
    hipLaunchKernelGGL(k_inorm_prelu, dim3(Bc*128), dim3(256), 0, stream, u1, 0, 2500, a_u1, mode);
    // u2: C1=C2=128, NWC=2 NWM=2, LDS 70.1KB
    hipLaunchKernelGGL((k_convTG<66,2,2,128,136>), dim3(50, 1, Bc), dim3(512), 0, stream,
                       xs2, 0, u1, 0, wTu2, b_u2, u2, mode, 50, 50, 64);
    hipLaunchKernelGGL(k_inorm_prelu, dim3(Bc*64), dim3(256), 0, stream, u2, 0, 10000, a_u2, mode);
    // u3: C1=C2=64, NWC=1 NWM=4, LDS 73.1KB
    hipLaunchKernelGGL((k_convTG<130,1,4,64,72>), dim3(100, 1, Bc), dim3(512), 0, stream,
                       xs1, 0, u2, 0, wTu3, b_u3, u3, mode, 100, 100, 32);
    hipLaunchKernelGGL(k_inorm_prelu, dim3(Bc*32), dim3(256), 0, stream, u3, 0, 40000, a_u3, mode);
    // u4: vectorized VALU head
    hipLaunchKernelGGL(k_convT8, dim3(40, 1, Bc), dim3(256), 0, stream,
                       xs0, u3, w_u4, b_u4, d_out, out_off, 2, mode, 200, 200);
  }
}